// Round 1
// baseline (174.256 us; speedup 1.0000x reference)
//
#include <hip/hip_runtime.h>
#include <math.h>

#define BB   256   // batch
#define OBS  256
#define HH   1024
#define AA   18

// ---------------------------------------------------------------------------
// fc_in: h1T[o][b] = dot(x[b,:], W_in[o,:]) + b_in[o]
// grid (B/64, H/16), block 256. lane=b, each wave owns 4 o-rows (scalar W).
// x rows read as per-thread float4 streams (64-row gather, L1-resident).
// ---------------------------------------------------------------------------
__global__ __launch_bounds__(256) void fc_in_kernel(
    const float* __restrict__ x, const float* __restrict__ Wi,
    const float* __restrict__ bi, float* __restrict__ h1T) {
  const int lane = threadIdx.x & 63;
  const int wid  = __builtin_amdgcn_readfirstlane(threadIdx.x >> 6);
  const int b    = blockIdx.x * 64 + lane;
  const int o0   = blockIdx.y * 16 + wid * 4;

  const float4* __restrict__ xr = (const float4*)(x + (size_t)b * OBS);
  const float4* __restrict__ w0 = (const float4*)(Wi + (size_t)(o0 + 0) * OBS);
  const float4* __restrict__ w1 = (const float4*)(Wi + (size_t)(o0 + 1) * OBS);
  const float4* __restrict__ w2 = (const float4*)(Wi + (size_t)(o0 + 2) * OBS);
  const float4* __restrict__ w3 = (const float4*)(Wi + (size_t)(o0 + 3) * OBS);

  float a0 = bi[o0 + 0], a1 = bi[o0 + 1], a2 = bi[o0 + 2], a3 = bi[o0 + 3];

#pragma unroll 8
  for (int kq = 0; kq < OBS / 4; ++kq) {
    const float4 xv = xr[kq];
    const float4 v0 = w0[kq];
    const float4 v1 = w1[kq];
    const float4 v2 = w2[kq];
    const float4 v3 = w3[kq];
    a0 = fmaf(xv.x, v0.x, a0); a0 = fmaf(xv.y, v0.y, a0);
    a0 = fmaf(xv.z, v0.z, a0); a0 = fmaf(xv.w, v0.w, a0);
    a1 = fmaf(xv.x, v1.x, a1); a1 = fmaf(xv.y, v1.y, a1);
    a1 = fmaf(xv.z, v1.z, a1); a1 = fmaf(xv.w, v1.w, a1);
    a2 = fmaf(xv.x, v2.x, a2); a2 = fmaf(xv.y, v2.y, a2);
    a2 = fmaf(xv.z, v2.z, a2); a2 = fmaf(xv.w, v2.w, a2);
    a3 = fmaf(xv.x, v3.x, a3); a3 = fmaf(xv.y, v3.y, a3);
    a3 = fmaf(xv.z, v3.z, a3); a3 = fmaf(xv.w, v3.w, a3);
  }

  h1T[(size_t)(o0 + 0) * BB + b] = a0;
  h1T[(size_t)(o0 + 1) * BB + b] = a1;
  h1T[(size_t)(o0 + 2) * BB + b] = a2;
  h1T[(size_t)(o0 + 3) * BB + b] = a3;
}

// ---------------------------------------------------------------------------
// max-plus / min-plus: outT[o][b] = OP_i( W[o][i] + inT[i][b] )
// grid (B/64, H/16), block 256. No LDS, no barriers.
// inT reads: lane-consecutive (coalesced). W reads: wave-uniform (scalar).
// Pairwise i so the compiler can form v_max3/v_min3.
// ---------------------------------------------------------------------------
template <bool IS_MAX>
__global__ __launch_bounds__(256) void mmplus_kernel(
    const float* __restrict__ inT, const float* __restrict__ W,
    float* __restrict__ outT) {
  const int lane = threadIdx.x & 63;
  const int wid  = __builtin_amdgcn_readfirstlane(threadIdx.x >> 6);
  const int b    = blockIdx.x * 64 + lane;
  const int o0   = blockIdx.y * 16 + wid * 4;

  const float* __restrict__ w0 = W + (size_t)(o0 + 0) * HH;
  const float* __restrict__ w1 = W + (size_t)(o0 + 1) * HH;
  const float* __restrict__ w2 = W + (size_t)(o0 + 2) * HH;
  const float* __restrict__ w3 = W + (size_t)(o0 + 3) * HH;

  const float init = IS_MAX ? -INFINITY : INFINITY;
  float a0 = init, a1 = init, a2 = init, a3 = init;

#pragma unroll 8
  for (int i = 0; i < HH; i += 2) {
    const float h0 = inT[(size_t)i * BB + b];
    const float h1 = inT[(size_t)(i + 1) * BB + b];
    if (IS_MAX) {
      a0 = fmaxf(a0, fmaxf(w0[i] + h0, w0[i + 1] + h1));
      a1 = fmaxf(a1, fmaxf(w1[i] + h0, w1[i + 1] + h1));
      a2 = fmaxf(a2, fmaxf(w2[i] + h0, w2[i + 1] + h1));
      a3 = fmaxf(a3, fmaxf(w3[i] + h0, w3[i + 1] + h1));
    } else {
      a0 = fminf(a0, fminf(w0[i] + h0, w0[i + 1] + h1));
      a1 = fminf(a1, fminf(w1[i] + h0, w1[i + 1] + h1));
      a2 = fminf(a2, fminf(w2[i] + h0, w2[i + 1] + h1));
      a3 = fminf(a3, fminf(w3[i] + h0, w3[i + 1] + h1));
    }
  }

  outT[(size_t)(o0 + 0) * BB + b] = a0;
  outT[(size_t)(o0 + 1) * BB + b] = a1;
  outT[(size_t)(o0 + 2) * BB + b] = a2;
  outT[(size_t)(o0 + 3) * BB + b] = a3;
}

// ---------------------------------------------------------------------------
// fc_out: q[b][a] += dot(h3T[ks*256:(ks+1)*256][b], W_out[a, ks*256:...])
// grid (A, 4) K-split, block 256 (thread = b). d_out pre-zeroed by memset.
// ---------------------------------------------------------------------------
__global__ __launch_bounds__(256) void fc_out_kernel(
    const float* __restrict__ h3T, const float* __restrict__ Wo,
    const float* __restrict__ bo, float* __restrict__ q) {
  const int a  = blockIdx.x;
  const int ks = blockIdx.y;
  const int t  = threadIdx.x;

  const float* __restrict__ w  = Wo + (size_t)a * HH + (size_t)ks * 256;
  const float* __restrict__ hp = h3T + (size_t)ks * 256 * BB + t;

  float acc = 0.0f;
#pragma unroll 8
  for (int i = 0; i < 256; ++i) {
    acc = fmaf(w[i], hp[(size_t)i * BB], acc);
  }
  if (ks == 0) acc += bo[a];
  atomicAdd(q + (size_t)t * AA + a, acc);
}

// ---------------------------------------------------------------------------
extern "C" void kernel_launch(void* const* d_in, const int* in_sizes, int n_in,
                              void* d_out, int out_size, void* d_ws, size_t ws_size,
                              hipStream_t stream) {
  const float* x    = (const float*)d_in[0];
  const float* Wi   = (const float*)d_in[1];
  const float* bi   = (const float*)d_in[2];
  const float* Wmax = (const float*)d_in[3];
  const float* Wmin = (const float*)d_in[4];
  const float* Wo   = (const float*)d_in[5];
  const float* bo   = (const float*)d_in[6];
  float* q = (float*)d_out;

  float* h1T = (float*)d_ws;            // [H][B] = 1 MB
  float* h2T = h1T + (size_t)BB * HH;   // [H][B]
  float* h3T = h2T + (size_t)BB * HH;   // [H][B]

  hipMemsetAsync(d_out, 0, (size_t)BB * AA * sizeof(float), stream);

  fc_in_kernel<<<dim3(BB / 64, HH / 16), 256, 0, stream>>>(x, Wi, bi, h1T);
  mmplus_kernel<true ><<<dim3(BB / 64, HH / 16), 256, 0, stream>>>(h1T, Wmax, h2T);
  mmplus_kernel<false><<<dim3(BB / 64, HH / 16), 256, 0, stream>>>(h2T, Wmin, h3T);
  fc_out_kernel<<<dim3(AA, 4), 256, 0, stream>>>(h3T, Wo, bo, q);
}

// Round 2
// 122.385 us; speedup vs baseline: 1.4238x; 1.4238x over previous
//
#include <hip/hip_runtime.h>
#include <math.h>

#define BB   256   // batch
#define OBS  256
#define HH   1024
#define AA   18

// ---------------------------------------------------------------------------
// fc_in: h1T[o][b] = dot(x[b,:], W_in[o,:]) + b_in[o]
// grid (H/16, B/64), block 1024 = 16 waves = 2 o-octets x 8 k-splits.
// lane = b. W loads wave-uniform -> s_load. LDS combine of 8 k-partials.
// ---------------------------------------------------------------------------
__global__ __launch_bounds__(1024) void fc_in_kernel(
    const float* __restrict__ x, const float* __restrict__ Wi,
    const float* __restrict__ bi, float* __restrict__ h1T) {
  __shared__ float red[8][16][64];  // [k-split][o-in-block][b-lane] = 32 KB
  const int lane = threadIdx.x & 63;
  const int wv   = __builtin_amdgcn_readfirstlane(threadIdx.x >> 6);
  const int oq   = wv & 1;   // which o-octet
  const int s    = wv >> 1;  // which k-split (32 k each)
  const int og   = blockIdx.x;   // 0..63  (x-major: W-sharing blocks -> same XCD)
  const int bg   = blockIdx.y;   // 0..3
  const int b    = bg * 64 + lane;
  const int o0   = og * 16 + oq * 8;

  const float4* __restrict__ xr = (const float4*)(x + (size_t)b * OBS + s * 32);
  const float4* __restrict__ w0 = (const float4*)(Wi + (size_t)(o0 + 0) * OBS + s * 32);
  const float4* __restrict__ w1 = (const float4*)(Wi + (size_t)(o0 + 1) * OBS + s * 32);
  const float4* __restrict__ w2 = (const float4*)(Wi + (size_t)(o0 + 2) * OBS + s * 32);
  const float4* __restrict__ w3 = (const float4*)(Wi + (size_t)(o0 + 3) * OBS + s * 32);
  const float4* __restrict__ w4 = (const float4*)(Wi + (size_t)(o0 + 4) * OBS + s * 32);
  const float4* __restrict__ w5 = (const float4*)(Wi + (size_t)(o0 + 5) * OBS + s * 32);
  const float4* __restrict__ w6 = (const float4*)(Wi + (size_t)(o0 + 6) * OBS + s * 32);
  const float4* __restrict__ w7 = (const float4*)(Wi + (size_t)(o0 + 7) * OBS + s * 32);

  float a0 = 0, a1 = 0, a2 = 0, a3 = 0, a4 = 0, a5 = 0, a6 = 0, a7 = 0;

#pragma unroll
  for (int kq = 0; kq < 8; ++kq) {
    const float4 xv = xr[kq];
#define DOT4(acc, wp)                                         \
    { const float4 v = wp[kq];                                \
      acc = fmaf(xv.x, v.x, acc); acc = fmaf(xv.y, v.y, acc); \
      acc = fmaf(xv.z, v.z, acc); acc = fmaf(xv.w, v.w, acc); }
    DOT4(a0, w0) DOT4(a1, w1) DOT4(a2, w2) DOT4(a3, w3)
    DOT4(a4, w4) DOT4(a5, w5) DOT4(a6, w6) DOT4(a7, w7)
#undef DOT4
  }

  red[s][oq * 8 + 0][lane] = a0;
  red[s][oq * 8 + 1][lane] = a1;
  red[s][oq * 8 + 2][lane] = a2;
  red[s][oq * 8 + 3][lane] = a3;
  red[s][oq * 8 + 4][lane] = a4;
  red[s][oq * 8 + 5][lane] = a5;
  red[s][oq * 8 + 6][lane] = a6;
  red[s][oq * 8 + 7][lane] = a7;
  __syncthreads();

  // one output element per thread: o_local = wv, b = lane
  const int ol = wv;
  float m = red[0][ol][lane];
#pragma unroll
  for (int t = 1; t < 8; ++t) m += red[t][ol][lane];
  m += bi[og * 16 + ol];
  h1T[(size_t)(og * 16 + ol) * BB + b] = m;
}

// ---------------------------------------------------------------------------
// max-plus / min-plus: outT[o][b] = OP_i( W[o][i] + inT[i][b] )
// grid (H/16, B/64), block 1024 = 16 waves = 2 o-octets x 8 i-splits (128 i).
// inT reads lane-coalesced, W reads wave-uniform (scalar), LDS combine.
// Pairwise i -> v_max3/v_min3 (1.5 VALU instr / element).
// ---------------------------------------------------------------------------
template <bool IS_MAX>
__global__ __launch_bounds__(1024) void mmplus_kernel(
    const float* __restrict__ inT, const float* __restrict__ W,
    float* __restrict__ outT) {
  __shared__ float red[8][16][64];  // 32 KB
  const int lane = threadIdx.x & 63;
  const int wv   = __builtin_amdgcn_readfirstlane(threadIdx.x >> 6);
  const int oq   = wv & 1;
  const int s    = wv >> 1;           // i-split: 128 i's each
  const int og   = blockIdx.x;        // x-major: same-W blocks on same XCD
  const int bg   = blockIdx.y;
  const int b    = bg * 64 + lane;
  const int o0   = og * 16 + oq * 8;
  const int i0   = s * 128;

  const float* __restrict__ w0 = W + (size_t)(o0 + 0) * HH + i0;
  const float* __restrict__ w1 = W + (size_t)(o0 + 1) * HH + i0;
  const float* __restrict__ w2 = W + (size_t)(o0 + 2) * HH + i0;
  const float* __restrict__ w3 = W + (size_t)(o0 + 3) * HH + i0;
  const float* __restrict__ w4 = W + (size_t)(o0 + 4) * HH + i0;
  const float* __restrict__ w5 = W + (size_t)(o0 + 5) * HH + i0;
  const float* __restrict__ w6 = W + (size_t)(o0 + 6) * HH + i0;
  const float* __restrict__ w7 = W + (size_t)(o0 + 7) * HH + i0;
  const float* __restrict__ hp = inT + (size_t)i0 * BB + b;

  const float init = IS_MAX ? -INFINITY : INFINITY;
  float a0 = init, a1 = init, a2 = init, a3 = init;
  float a4 = init, a5 = init, a6 = init, a7 = init;

#pragma unroll 8
  for (int ii = 0; ii < 128; ii += 2) {
    const float h0 = hp[(size_t)ii * BB];
    const float h1 = hp[(size_t)(ii + 1) * BB];
    if (IS_MAX) {
      a0 = fmaxf(a0, fmaxf(w0[ii] + h0, w0[ii + 1] + h1));
      a1 = fmaxf(a1, fmaxf(w1[ii] + h0, w1[ii + 1] + h1));
      a2 = fmaxf(a2, fmaxf(w2[ii] + h0, w2[ii + 1] + h1));
      a3 = fmaxf(a3, fmaxf(w3[ii] + h0, w3[ii + 1] + h1));
      a4 = fmaxf(a4, fmaxf(w4[ii] + h0, w4[ii + 1] + h1));
      a5 = fmaxf(a5, fmaxf(w5[ii] + h0, w5[ii + 1] + h1));
      a6 = fmaxf(a6, fmaxf(w6[ii] + h0, w6[ii + 1] + h1));
      a7 = fmaxf(a7, fmaxf(w7[ii] + h0, w7[ii + 1] + h1));
    } else {
      a0 = fminf(a0, fminf(w0[ii] + h0, w0[ii + 1] + h1));
      a1 = fminf(a1, fminf(w1[ii] + h0, w1[ii + 1] + h1));
      a2 = fminf(a2, fminf(w2[ii] + h0, w2[ii + 1] + h1));
      a3 = fminf(a3, fminf(w3[ii] + h0, w3[ii + 1] + h1));
      a4 = fminf(a4, fminf(w4[ii] + h0, w4[ii + 1] + h1));
      a5 = fminf(a5, fminf(w5[ii] + h0, w5[ii + 1] + h1));
      a6 = fminf(a6, fminf(w6[ii] + h0, w6[ii + 1] + h1));
      a7 = fminf(a7, fminf(w7[ii] + h0, w7[ii + 1] + h1));
    }
  }

  red[s][oq * 8 + 0][lane] = a0;
  red[s][oq * 8 + 1][lane] = a1;
  red[s][oq * 8 + 2][lane] = a2;
  red[s][oq * 8 + 3][lane] = a3;
  red[s][oq * 8 + 4][lane] = a4;
  red[s][oq * 8 + 5][lane] = a5;
  red[s][oq * 8 + 6][lane] = a6;
  red[s][oq * 8 + 7][lane] = a7;
  __syncthreads();

  const int ol = wv;
  float m = red[0][ol][lane];
#pragma unroll
  for (int t = 1; t < 8; ++t)
    m = IS_MAX ? fmaxf(m, red[t][ol][lane]) : fminf(m, red[t][ol][lane]);
  outT[(size_t)(og * 16 + ol) * BB + b] = m;
}

// ---------------------------------------------------------------------------
// fc_out: q[b][a] = bo[a] + dot(h3T[:, b], W_out[a, :])
// grid (A), block 1024 = 4 k-splits x 256 b. No atomics, no memset.
// ---------------------------------------------------------------------------
__global__ __launch_bounds__(1024) void fc_out_kernel(
    const float* __restrict__ h3T, const float* __restrict__ Wo,
    const float* __restrict__ bo, float* __restrict__ q) {
  __shared__ float red[4][256];
  const int a  = blockIdx.x;
  const int t  = threadIdx.x;
  const int ks = t >> 8;    // wave-uniform
  const int b  = t & 255;

  const float* __restrict__ w  = Wo + (size_t)a * HH + (size_t)ks * 256;
  const float* __restrict__ hp = h3T + (size_t)ks * 256 * BB + b;

  float acc = 0.0f;
#pragma unroll 8
  for (int i = 0; i < 256; ++i) {
    acc = fmaf(w[i], hp[(size_t)i * BB], acc);
  }
  red[ks][b] = acc;
  __syncthreads();

  if (t < 256) {
    const float m = red[0][t] + red[1][t] + red[2][t] + red[3][t] + bo[a];
    q[(size_t)t * AA + a] = m;
  }
}

// ---------------------------------------------------------------------------
extern "C" void kernel_launch(void* const* d_in, const int* in_sizes, int n_in,
                              void* d_out, int out_size, void* d_ws, size_t ws_size,
                              hipStream_t stream) {
  const float* x    = (const float*)d_in[0];
  const float* Wi   = (const float*)d_in[1];
  const float* bi   = (const float*)d_in[2];
  const float* Wmax = (const float*)d_in[3];
  const float* Wmin = (const float*)d_in[4];
  const float* Wo   = (const float*)d_in[5];
  const float* bo   = (const float*)d_in[6];
  float* q = (float*)d_out;

  float* h1T = (float*)d_ws;            // [H][B] = 1 MB
  float* h2T = h1T + (size_t)BB * HH;
  float* h3T = h2T + (size_t)BB * HH;

  fc_in_kernel<<<dim3(HH / 16, BB / 64), 1024, 0, stream>>>(x, Wi, bi, h1T);
  mmplus_kernel<true ><<<dim3(HH / 16, BB / 64), 1024, 0, stream>>>(h1T, Wmax, h2T);
  mmplus_kernel<false><<<dim3(HH / 16, BB / 64), 1024, 0, stream>>>(h2T, Wmin, h3T);
  fc_out_kernel<<<AA, 1024, 0, stream>>>(h3T, Wo, bo, q);
}

// Round 4
// 111.794 us; speedup vs baseline: 1.5587x; 1.0947x over previous
//
#include <hip/hip_runtime.h>
#include <math.h>

#define BB   256   // batch
#define OBS  256
#define HH   1024
#define AA   18

// clang-native packed f16: + -> v_pk_add_f16, elementwise_max -> v_pk_max_f16
typedef _Float16 h2 __attribute__((ext_vector_type(2)));

static __device__ __forceinline__ h2 u2h(unsigned int u) {
  return __builtin_bit_cast(h2, u);
}
static __device__ __forceinline__ unsigned int h2u(h2 v) {
  return __builtin_bit_cast(unsigned int, v);
}

// ---------------------------------------------------------------------------
// prep: W_max/W_min f32 -> packed f16 dwords (adjacent i pairs), and
// transpose x -> xT[k][b] so fc_in's per-lane (lane=b) reads coalesce.
// ---------------------------------------------------------------------------
__global__ __launch_bounds__(256) void prep_kernel(
    const float* __restrict__ x, const float* __restrict__ Wmax,
    const float* __restrict__ Wmin, float* __restrict__ xT,
    unsigned int* __restrict__ Wmax16, unsigned int* __restrict__ Wmin16) {
  const int id = blockIdx.x * 256 + threadIdx.x;
  const int NW = (HH * HH) / 4;  // float4 quads per W matrix
  if (id < NW) {
    const float4 v = ((const float4*)Wmax)[id];
    h2 p0 = {(_Float16)v.x, (_Float16)v.y};
    h2 p1 = {(_Float16)v.z, (_Float16)v.w};
    Wmax16[id * 2]     = h2u(p0);
    Wmax16[id * 2 + 1] = h2u(p1);
  } else if (id < 2 * NW) {
    const int j = id - NW;
    const float4 v = ((const float4*)Wmin)[j];
    h2 p0 = {(_Float16)v.x, (_Float16)v.y};
    h2 p1 = {(_Float16)v.z, (_Float16)v.w};
    Wmin16[j * 2]     = h2u(p0);
    Wmin16[j * 2 + 1] = h2u(p1);
  } else {
    const int j = id - 2 * NW;               // 0 .. OBS*BB-1
    if (j < OBS * BB) {
      const int k = j >> 8, b = j & 255;     // write coalesced, read gather (L2)
      xT[(size_t)k * BB + b] = x[(size_t)b * OBS + k];
    }
  }
}

// ---------------------------------------------------------------------------
// fc_in: h1pk[o/2][b] = pack_f16( x@W_in^T + b_in ) for o-pair
// grid (H/16, B/64), block 1024 = 8 k-splits x 2 o-octets. lane = b.
// xT reads coalesced; W_in rows wave-uniform -> s_load. LDS combine.
// ---------------------------------------------------------------------------
__global__ __launch_bounds__(1024) void fc_in_kernel(
    const float* __restrict__ xT, const float* __restrict__ Wi,
    const float* __restrict__ bi, unsigned int* __restrict__ h1pk) {
  __shared__ float red[8][16][64];  // [k-split][o-local][b-lane] = 32 KB
  const int t    = threadIdx.x;
  const int lane = t & 63;
  const int wv   = __builtin_amdgcn_readfirstlane(t >> 6);
  const int oq   = wv & 1;
  const int s    = wv >> 1;        // k-split: 32 k each
  const int og   = blockIdx.x;
  const int bg   = blockIdx.y;
  const int b    = bg * 64 + lane;
  const int o0   = og * 16 + oq * 8;
  const int k0   = s * 32;

  const float* __restrict__ w0 = Wi + (size_t)(o0 + 0) * OBS + k0;
  const float* __restrict__ w1 = Wi + (size_t)(o0 + 1) * OBS + k0;
  const float* __restrict__ w2 = Wi + (size_t)(o0 + 2) * OBS + k0;
  const float* __restrict__ w3 = Wi + (size_t)(o0 + 3) * OBS + k0;
  const float* __restrict__ w4 = Wi + (size_t)(o0 + 4) * OBS + k0;
  const float* __restrict__ w5 = Wi + (size_t)(o0 + 5) * OBS + k0;
  const float* __restrict__ w6 = Wi + (size_t)(o0 + 6) * OBS + k0;
  const float* __restrict__ w7 = Wi + (size_t)(o0 + 7) * OBS + k0;
  const float* __restrict__ xp = xT + (size_t)k0 * BB + b;

  float a0 = 0, a1 = 0, a2 = 0, a3 = 0, a4 = 0, a5 = 0, a6 = 0, a7 = 0;
#pragma unroll 8
  for (int k = 0; k < 32; ++k) {
    const float xv = xp[(size_t)k * BB];
    a0 = fmaf(xv, w0[k], a0); a1 = fmaf(xv, w1[k], a1);
    a2 = fmaf(xv, w2[k], a2); a3 = fmaf(xv, w3[k], a3);
    a4 = fmaf(xv, w4[k], a4); a5 = fmaf(xv, w5[k], a5);
    a6 = fmaf(xv, w6[k], a6); a7 = fmaf(xv, w7[k], a7);
  }

  red[s][oq * 8 + 0][lane] = a0;  red[s][oq * 8 + 1][lane] = a1;
  red[s][oq * 8 + 2][lane] = a2;  red[s][oq * 8 + 3][lane] = a3;
  red[s][oq * 8 + 4][lane] = a4;  red[s][oq * 8 + 5][lane] = a5;
  red[s][oq * 8 + 6][lane] = a6;  red[s][oq * 8 + 7][lane] = a7;
  __syncthreads();

  if (t < 512) {
    const int op = t >> 6;       // block-local o-pair 0..7 (uniform per wave)
    const int bl = t & 63;
    float s0 = 0.f, s1 = 0.f;
#pragma unroll
    for (int ks = 0; ks < 8; ++ks) {
      s0 += red[ks][2 * op][bl];
      s1 += red[ks][2 * op + 1][bl];
    }
    s0 += bi[og * 16 + 2 * op];
    s1 += bi[og * 16 + 2 * op + 1];
    h2 p = {(_Float16)s0, (_Float16)s1};
    h1pk[(size_t)(og * 8 + op) * BB + bg * 64 + bl] = h2u(p);
  }
}

// ---------------------------------------------------------------------------
// mmplus (packed f16): out[o][b] = OP_i( W[o][i] + h[i][b] )
// grid (H/16, B/64), block 1024 = 16 i-splits (64 i each). Thread tile 4o x 4b.
// W tile (16 o x 512 pk-dwords) staged in LDS, pitch 514 (conflict-free,
// even for b64 reads). Staging: stride-64 interleave -> 2 lanes/bank (free).
// h read as coalesced dwordx4 (4 b). v_pk_add_f16 + v_pk_max/min_f16.
// ---------------------------------------------------------------------------
template <bool IS_MAX>
__global__ __launch_bounds__(1024) void mmplus_kernel(
    const unsigned int* __restrict__ hpk,   // [H/2][B] dwords (i-pair, b)
    const unsigned int* __restrict__ W16,   // [H][H/2] dwords (o, i-pair)
    unsigned int* __restrict__ opk) {       // [H/2][B]
  constexpr int PITCH = 514;
  __shared__ __align__(16) unsigned int lds[16 * PITCH];  // 32.9 KB; red aliases
  const int t    = threadIdx.x;
  const int lane = t & 63;
  const int og2  = lane >> 4;      // o-quad 0..3
  const int bq   = lane & 15;      // b-quad 0..15
  const int s    = __builtin_amdgcn_readfirstlane(t >> 6);  // i-split 0..15
  const int og   = blockIdx.x;
  const int bg   = blockIdx.y;

  // ---- stage W tile: 16 rows (one per wave) x 512 pk-dwords ----
  {
    const int o_l = t >> 6;        // row per wave
    const int c   = t & 63;
    const unsigned int* src = W16 + (size_t)(og * 16 + o_l) * (HH / 2);
    unsigned int* dst = &lds[o_l * PITCH];
#pragma unroll
    for (int k = 0; k < 8; ++k)    // stride-64: coalesced global, 2 lanes/bank LDS
      dst[c + 64 * k] = src[c + 64 * k];
  }
  __syncthreads();

  const unsigned int* __restrict__ hp = hpk + (size_t)(s * 32) * BB + bg * 64 + bq * 4;
  const _Float16 INIT = (_Float16)(IS_MAX ? -65504.f : 65504.f);
  h2 acc[4][4];
#pragma unroll
  for (int j = 0; j < 4; ++j)
#pragma unroll
    for (int bb = 0; bb < 4; ++bb) acc[j][bb] = (h2){INIT, INIT};

  // 32 i-pairs for this split, 2 pairs (4 i) per iteration
#pragma unroll 4
  for (int it = 0; it < 16; ++it) {
    const int p = it * 2;
    const uint4 h0 = *(const uint4*)(hp + (size_t)p * BB);
    const uint4 h1 = *(const uint4*)(hp + (size_t)(p + 1) * BB);
    const h2 h0v[4] = {u2h(h0.x), u2h(h0.y), u2h(h0.z), u2h(h0.w)};
    const h2 h1v[4] = {u2h(h1.x), u2h(h1.y), u2h(h1.z), u2h(h1.w)};
#pragma unroll
    for (int j = 0; j < 4; ++j) {
      const uint2 wj = *(const uint2*)&lds[(og2 * 4 + j) * PITCH + s * 32 + p];
      const h2 wa = u2h(wj.x);   // pair (i, i+1)
      const h2 wb = u2h(wj.y);   // pair (i+2, i+3)
#pragma unroll
      for (int bb = 0; bb < 4; ++bb) {
        if (IS_MAX) {
          acc[j][bb] = __builtin_elementwise_max(acc[j][bb], wa + h0v[bb]);
          acc[j][bb] = __builtin_elementwise_max(acc[j][bb], wb + h1v[bb]);
        } else {
          acc[j][bb] = __builtin_elementwise_min(acc[j][bb], wa + h0v[bb]);
          acc[j][bb] = __builtin_elementwise_min(acc[j][bb], wb + h1v[bb]);
        }
      }
    }
  }

  // fold even/odd i-partials -> scalar f16 per (o,b), pack o-pairs
  unsigned int opack[2][4];  // [o-pair][b]
#pragma unroll
  for (int jp = 0; jp < 2; ++jp)
#pragma unroll
    for (int bb = 0; bb < 4; ++bb) {
      const h2 ae = acc[2 * jp][bb], ao = acc[2 * jp + 1][bb];
      const _Float16 me = IS_MAX ? (ae.x > ae.y ? ae.x : ae.y)
                                 : (ae.x < ae.y ? ae.x : ae.y);
      const _Float16 mo = IS_MAX ? (ao.x > ao.y ? ao.x : ao.y)
                                 : (ao.x < ao.y ? ao.x : ao.y);
      opack[jp][bb] = h2u((h2){me, mo});
    }

  __syncthreads();  // all W reads done; reuse lds[] as red[16][8][64]
#pragma unroll
  for (int jp = 0; jp < 2; ++jp) {
    const int op = og2 * 2 + jp;
#pragma unroll
    for (int bb = 0; bb < 4; ++bb)
      lds[s * 512 + op * 64 + bq * 4 + bb] = opack[jp][bb];
  }
  __syncthreads();

  if (t < 512) {
    const int op = t >> 6;   // 0..7
    const int bl = t & 63;
    h2 m = u2h(lds[op * 64 + bl]);
#pragma unroll
    for (int ks = 1; ks < 16; ++ks) {
      const h2 v = u2h(lds[ks * 512 + op * 64 + bl]);
      m = IS_MAX ? __builtin_elementwise_max(m, v)
                 : __builtin_elementwise_min(m, v);
    }
    opk[(size_t)(og * 8 + op) * BB + bg * 64 + bl] = h2u(m);
  }
}

// ---------------------------------------------------------------------------
// fc_out: q[b][a] = bo[a] + dot(h3[:,b], W_out[a,:])
// grid (A, B/64), block 1024 = 16 k-splits x 64 b. W scalar, h coalesced pk.
// ---------------------------------------------------------------------------
__global__ __launch_bounds__(1024) void fc_out_kernel(
    const unsigned int* __restrict__ h3pk, const float* __restrict__ Wo,
    const float* __restrict__ bo, float* __restrict__ q) {
  __shared__ float red[16][64];
  const int a  = blockIdx.x;
  const int bg = blockIdx.y;
  const int t  = threadIdx.x;
  const int bl = t & 63;
  const int ks = __builtin_amdgcn_readfirstlane(t >> 6);  // 0..15, 32 pk-rows each

  const unsigned int* __restrict__ hp = h3pk + (size_t)(ks * 32) * BB + bg * 64 + bl;
  const float* __restrict__ w = Wo + (size_t)a * HH + ks * 64;

  float acc = 0.f;
#pragma unroll 8
  for (int d = 0; d < 32; ++d) {
    const h2 hv = u2h(hp[(size_t)d * BB]);
    acc = fmaf((float)hv.x, w[2 * d], acc);
    acc = fmaf((float)hv.y, w[2 * d + 1], acc);
  }
  red[ks][bl] = acc;
  __syncthreads();

  if (t < 64) {
    float m = bo[a];
#pragma unroll
    for (int ks2 = 0; ks2 < 16; ++ks2) m += red[ks2][t];
    q[(size_t)(bg * 64 + t) * AA + a] = m;
  }
}

// ---------------------------------------------------------------------------
extern "C" void kernel_launch(void* const* d_in, const int* in_sizes, int n_in,
                              void* d_out, int out_size, void* d_ws, size_t ws_size,
                              hipStream_t stream) {
  const float* x    = (const float*)d_in[0];
  const float* Wi   = (const float*)d_in[1];
  const float* bi   = (const float*)d_in[2];
  const float* Wmax = (const float*)d_in[3];
  const float* Wmin = (const float*)d_in[4];
  const float* Wo   = (const float*)d_in[5];
  const float* bo   = (const float*)d_in[6];
  float* q = (float*)d_out;

  char* ws = (char*)d_ws;
  float*        xT     = (float*)ws;          ws += (size_t)OBS * BB * 4;       // 256 KB
  unsigned int* Wmax16 = (unsigned int*)ws;   ws += (size_t)HH * (HH / 2) * 4;  // 2 MB
  unsigned int* Wmin16 = (unsigned int*)ws;   ws += (size_t)HH * (HH / 2) * 4;  // 2 MB
  unsigned int* h1pk   = (unsigned int*)ws;   ws += (size_t)(HH / 2) * BB * 4;  // 512 KB
  unsigned int* h2pk   = (unsigned int*)ws;   ws += (size_t)(HH / 2) * BB * 4;
  unsigned int* h3pk   = (unsigned int*)ws;

  const int prep_items = 2 * (HH * HH / 4) + OBS * BB;     // 589824
  prep_kernel<<<(prep_items + 255) / 256, 256, 0, stream>>>(
      x, Wmax, Wmin, xT, Wmax16, Wmin16);
  fc_in_kernel<<<dim3(HH / 16, BB / 64), 1024, 0, stream>>>(xT, Wi, bi, h1pk);
  mmplus_kernel<true ><<<dim3(HH / 16, BB / 64), 1024, 0, stream>>>(h1pk, Wmax16, h2pk);
  mmplus_kernel<false><<<dim3(HH / 16, BB / 64), 1024, 0, stream>>>(h2pk, Wmin16, h3pk);
  fc_out_kernel<<<dim3(AA, BB / 64), 1024, 0, stream>>>(h3pk, Wo, bo, q);
}

// Round 5
// 107.865 us; speedup vs baseline: 1.6155x; 1.0364x over previous
//
#include <hip/hip_runtime.h>
#include <math.h>

#define BB   256   // batch
#define OBS  256
#define HH   1024
#define AA   18

// clang-native packed f16: + -> v_pk_add_f16, elementwise_max -> v_pk_max_f16
typedef _Float16 h2 __attribute__((ext_vector_type(2)));

static __device__ __forceinline__ h2 u2h(unsigned int u) {
  return __builtin_bit_cast(h2, u);
}
static __device__ __forceinline__ unsigned int h2u(h2 v) {
  return __builtin_bit_cast(unsigned int, v);
}

// ---------------------------------------------------------------------------
// fc_in: h1pk[o/2][b] = pack_f16( x@W_in^T + b_in ) for o-pair
// grid (H/16, B/64), block 1024 = 8 k-splits x 2 o-octets. lane = b.
// x slice (64 rows x 256) self-staged via LDS (coalesced float4 row loads,
// pitch 257 -> compute reads 2 lanes/bank = free). W_in rows wave-uniform
// -> s_load. LDS combine of 8 k-partials.
// ---------------------------------------------------------------------------
__global__ __launch_bounds__(1024) void fc_in_kernel(
    const float* __restrict__ x, const float* __restrict__ Wi,
    const float* __restrict__ bi, unsigned int* __restrict__ h1pk) {
  __shared__ float xs[64][OBS + 1];   // 65.8 KB
  __shared__ float red[8][16][64];    // 32 KB
  const int t    = threadIdx.x;
  const int lane = t & 63;
  const int wv   = __builtin_amdgcn_readfirstlane(t >> 6);
  const int oq   = wv & 1;
  const int s    = wv >> 1;        // k-split: 32 k each
  const int og   = blockIdx.x;
  const int bg   = blockIdx.y;
  const int o0   = og * 16 + oq * 8;
  const int k0   = s * 32;

  // ---- stage x rows bg*64 .. +64: thread t handles row t>>4, 4 float4s ----
  {
    const int row = t >> 4;          // 0..63
    const int c4  = t & 15;          // 0..15
    const float4* src = (const float4*)(x + (size_t)(bg * 64 + row) * OBS);
#pragma unroll
    for (int k = 0; k < 4; ++k) {
      const float4 v = src[c4 + 16 * k];
      const int col = (c4 + 16 * k) * 4;
      xs[row][col]     = v.x;
      xs[row][col + 1] = v.y;
      xs[row][col + 2] = v.z;
      xs[row][col + 3] = v.w;
    }
  }
  __syncthreads();

  const float* __restrict__ w0 = Wi + (size_t)(o0 + 0) * OBS + k0;
  const float* __restrict__ w1 = Wi + (size_t)(o0 + 1) * OBS + k0;
  const float* __restrict__ w2 = Wi + (size_t)(o0 + 2) * OBS + k0;
  const float* __restrict__ w3 = Wi + (size_t)(o0 + 3) * OBS + k0;
  const float* __restrict__ w4 = Wi + (size_t)(o0 + 4) * OBS + k0;
  const float* __restrict__ w5 = Wi + (size_t)(o0 + 5) * OBS + k0;
  const float* __restrict__ w6 = Wi + (size_t)(o0 + 6) * OBS + k0;
  const float* __restrict__ w7 = Wi + (size_t)(o0 + 7) * OBS + k0;

  float a0 = 0, a1 = 0, a2 = 0, a3 = 0, a4 = 0, a5 = 0, a6 = 0, a7 = 0;
#pragma unroll 8
  for (int k = 0; k < 32; ++k) {
    const float xv = xs[lane][k0 + k];
    a0 = fmaf(xv, w0[k], a0); a1 = fmaf(xv, w1[k], a1);
    a2 = fmaf(xv, w2[k], a2); a3 = fmaf(xv, w3[k], a3);
    a4 = fmaf(xv, w4[k], a4); a5 = fmaf(xv, w5[k], a5);
    a6 = fmaf(xv, w6[k], a6); a7 = fmaf(xv, w7[k], a7);
  }

  red[s][oq * 8 + 0][lane] = a0;  red[s][oq * 8 + 1][lane] = a1;
  red[s][oq * 8 + 2][lane] = a2;  red[s][oq * 8 + 3][lane] = a3;
  red[s][oq * 8 + 4][lane] = a4;  red[s][oq * 8 + 5][lane] = a5;
  red[s][oq * 8 + 6][lane] = a6;  red[s][oq * 8 + 7][lane] = a7;
  __syncthreads();

  if (t < 512) {
    const int op = t >> 6;       // block-local o-pair 0..7 (uniform per wave)
    const int bl = t & 63;
    float s0 = 0.f, s1 = 0.f;
#pragma unroll
    for (int ks = 0; ks < 8; ++ks) {
      s0 += red[ks][2 * op][bl];
      s1 += red[ks][2 * op + 1][bl];
    }
    s0 += bi[og * 16 + 2 * op];
    s1 += bi[og * 16 + 2 * op + 1];
    h2 p = {(_Float16)s0, (_Float16)s1};
    h1pk[(size_t)(og * 8 + op) * BB + bg * 64 + bl] = h2u(p);
  }
}

// ---------------------------------------------------------------------------
// mmplus (packed f16): out[o][b] = OP_i( W[o][i] + h[i][b] )
// grid (H/16, B/64), block 1024 = 16 i-splits (64 i each). Thread tile 4o x 4b.
// W read as f32 and converted to packed f16 during LDS staging (no prep pass;
// the 4 blocks sharing a W tile are 64 apart in linear id == same XCD -> L2).
// LDS pitch 514: conflict-free b64 reads, even for alignment.
// h read as coalesced dwordx4. v_pk_add_f16 + v_pk_max/min_f16.
// ---------------------------------------------------------------------------
template <bool IS_MAX>
__global__ __launch_bounds__(1024) void mmplus_kernel(
    const unsigned int* __restrict__ hpk,   // [H/2][B] dwords (i-pair, b)
    const float* __restrict__ Wf,           // [H][H] f32 (o, i)
    unsigned int* __restrict__ opk) {       // [H/2][B]
  constexpr int PITCH = 514;
  __shared__ __align__(16) unsigned int lds[16 * PITCH];  // 32.9 KB; red aliases
  const int t    = threadIdx.x;
  const int lane = t & 63;
  const int og2  = lane >> 4;      // o-quad 0..3
  const int bq   = lane & 15;      // b-quad 0..15
  const int s    = __builtin_amdgcn_readfirstlane(t >> 6);  // i-split 0..15
  const int og   = blockIdx.x;
  const int bg   = blockIdx.y;

  // ---- stage W tile: 16 rows (one per wave), f32 -> pk f16 in-flight ----
  {
    const int o_l = t >> 6;        // row per wave
    const int c   = t & 63;
    const float4* src = (const float4*)(Wf + (size_t)(og * 16 + o_l) * HH);
    unsigned int* dst = &lds[o_l * PITCH];
#pragma unroll
    for (int k = 0; k < 4; ++k) {
      const float4 v = src[c + 64 * k];
      h2 p0 = {(_Float16)v.x, (_Float16)v.y};
      h2 p1 = {(_Float16)v.z, (_Float16)v.w};
      *(uint2*)&dst[(c + 64 * k) * 2] = make_uint2(h2u(p0), h2u(p1));
    }
  }
  __syncthreads();

  const unsigned int* __restrict__ hp = hpk + (size_t)(s * 32) * BB + bg * 64 + bq * 4;
  const _Float16 INIT = (_Float16)(IS_MAX ? -65504.f : 65504.f);
  h2 acc[4][4];
#pragma unroll
  for (int j = 0; j < 4; ++j)
#pragma unroll
    for (int bb = 0; bb < 4; ++bb) acc[j][bb] = (h2){INIT, INIT};

  // 32 i-pairs for this split, 2 pairs (4 i) per iteration
#pragma unroll 4
  for (int it = 0; it < 16; ++it) {
    const int p = it * 2;
    const uint4 h0 = *(const uint4*)(hp + (size_t)p * BB);
    const uint4 h1 = *(const uint4*)(hp + (size_t)(p + 1) * BB);
    const h2 h0v[4] = {u2h(h0.x), u2h(h0.y), u2h(h0.z), u2h(h0.w)};
    const h2 h1v[4] = {u2h(h1.x), u2h(h1.y), u2h(h1.z), u2h(h1.w)};
#pragma unroll
    for (int j = 0; j < 4; ++j) {
      const uint2 wj = *(const uint2*)&lds[(og2 * 4 + j) * PITCH + s * 32 + p];
      const h2 wa = u2h(wj.x);   // pair (i, i+1)
      const h2 wb = u2h(wj.y);   // pair (i+2, i+3)
#pragma unroll
      for (int bb = 0; bb < 4; ++bb) {
        if (IS_MAX) {
          acc[j][bb] = __builtin_elementwise_max(acc[j][bb], wa + h0v[bb]);
          acc[j][bb] = __builtin_elementwise_max(acc[j][bb], wb + h1v[bb]);
        } else {
          acc[j][bb] = __builtin_elementwise_min(acc[j][bb], wa + h0v[bb]);
          acc[j][bb] = __builtin_elementwise_min(acc[j][bb], wb + h1v[bb]);
        }
      }
    }
  }

  // fold even/odd i-partials -> scalar f16 per (o,b), pack o-pairs
  unsigned int opack[2][4];  // [o-pair][b]
#pragma unroll
  for (int jp = 0; jp < 2; ++jp)
#pragma unroll
    for (int bb = 0; bb < 4; ++bb) {
      const h2 ae = acc[2 * jp][bb], ao = acc[2 * jp + 1][bb];
      const _Float16 me = IS_MAX ? (ae.x > ae.y ? ae.x : ae.y)
                                 : (ae.x < ae.y ? ae.x : ae.y);
      const _Float16 mo = IS_MAX ? (ao.x > ao.y ? ao.x : ao.y)
                                 : (ao.x < ao.y ? ao.x : ao.y);
      opack[jp][bb] = h2u((h2){me, mo});
    }

  __syncthreads();  // all W reads done; reuse lds[] as red[16][8][64]
#pragma unroll
  for (int jp = 0; jp < 2; ++jp) {
    const int op = og2 * 2 + jp;
#pragma unroll
    for (int bb = 0; bb < 4; ++bb)
      lds[s * 512 + op * 64 + bq * 4 + bb] = opack[jp][bb];
  }
  __syncthreads();

  if (t < 512) {
    const int op = t >> 6;   // 0..7
    const int bl = t & 63;
    h2 m = u2h(lds[op * 64 + bl]);
#pragma unroll
    for (int ks = 1; ks < 16; ++ks) {
      const h2 v = u2h(lds[ks * 512 + op * 64 + bl]);
      m = IS_MAX ? __builtin_elementwise_max(m, v)
                 : __builtin_elementwise_min(m, v);
    }
    opk[(size_t)(og * 8 + op) * BB + bg * 64 + bl] = h2u(m);
  }
}

// ---------------------------------------------------------------------------
// fc_out: q[b][a] = bo[a] + dot(h3[:,b], W_out[a,:])
// grid (A, B/64), block 1024 = 16 k-splits x 64 b. W scalar, h coalesced pk.
// ---------------------------------------------------------------------------
__global__ __launch_bounds__(1024) void fc_out_kernel(
    const unsigned int* __restrict__ h3pk, const float* __restrict__ Wo,
    const float* __restrict__ bo, float* __restrict__ q) {
  __shared__ float red[16][64];
  const int a  = blockIdx.x;
  const int bg = blockIdx.y;
  const int t  = threadIdx.x;
  const int bl = t & 63;
  const int ks = __builtin_amdgcn_readfirstlane(t >> 6);  // 0..15, 32 pk-rows each

  const unsigned int* __restrict__ hp = h3pk + (size_t)(ks * 32) * BB + bg * 64 + bl;
  const float* __restrict__ w = Wo + (size_t)a * HH + ks * 64;

  float acc = 0.f;
#pragma unroll 8
  for (int d = 0; d < 32; ++d) {
    const h2 hv = u2h(hp[(size_t)d * BB]);
    acc = fmaf((float)hv.x, w[2 * d], acc);
    acc = fmaf((float)hv.y, w[2 * d + 1], acc);
  }
  red[ks][bl] = acc;
  __syncthreads();

  if (t < 64) {
    float m = bo[a];
#pragma unroll
    for (int ks2 = 0; ks2 < 16; ++ks2) m += red[ks2][t];
    q[(size_t)(bg * 64 + t) * AA + a] = m;
  }
}

// ---------------------------------------------------------------------------
extern "C" void kernel_launch(void* const* d_in, const int* in_sizes, int n_in,
                              void* d_out, int out_size, void* d_ws, size_t ws_size,
                              hipStream_t stream) {
  const float* x    = (const float*)d_in[0];
  const float* Wi   = (const float*)d_in[1];
  const float* bi   = (const float*)d_in[2];
  const float* Wmax = (const float*)d_in[3];
  const float* Wmin = (const float*)d_in[4];
  const float* Wo   = (const float*)d_in[5];
  const float* bo   = (const float*)d_in[6];
  float* q = (float*)d_out;

  char* ws = (char*)d_ws;
  unsigned int* h1pk = (unsigned int*)ws;   ws += (size_t)(HH / 2) * BB * 4;  // 512 KB
  unsigned int* h2pk = (unsigned int*)ws;   ws += (size_t)(HH / 2) * BB * 4;
  unsigned int* h3pk = (unsigned int*)ws;

  fc_in_kernel<<<dim3(HH / 16, BB / 64), 1024, 0, stream>>>(x, Wi, bi, h1pk);
  mmplus_kernel<true ><<<dim3(HH / 16, BB / 64), 1024, 0, stream>>>(h1pk, Wmax, h2pk);
  mmplus_kernel<false><<<dim3(HH / 16, BB / 64), 1024, 0, stream>>>(h2pk, Wmin, h3pk);
  fc_out_kernel<<<dim3(AA, BB / 64), 1024, 0, stream>>>(h3pk, Wo, bo, q);
}